// Round 3
// baseline (1013.020 us; speedup 1.0000x reference)
//
#include <hip/hip_runtime.h>
#include <math.h>

#define FHh 480
#define FWw 640
#define NPIX (FHh*FWw)          // 307200
#define NSEMC 16
#define COBS 20
#define MAPC 480
#define VRc 100
#define HZc 80
#define MINZc 13
#define MAXZc 25
#define ZW 12
#define NB 4
#define NBINS_DIM 101
#define NBINS_ROW 101
#define COUNTS_PAD 20480        // >= 2*101*101 = 20402, = 1024*20

// ---------------- pose + affine params ----------------
__global__ void pose_kernel(const float* __restrict__ pose_obs,
                            const float* __restrict__ poses_last,
                            float* __restrict__ out_p1,
                            float* __restrict__ out_p2,
                            float* __restrict__ params)
{
    int b = threadIdx.x;
    if (b >= NB) return;
    float pl0 = poses_last[b*3+0], pl1 = poses_last[b*3+1], pl2 = poses_last[b*3+2];
    float po0 = pose_obs[b*3+0],  po1 = pose_obs[b*3+1],  po2 = pose_obs[b*3+2];
    const float DEGf = 57.29577951308232f;
    float t0 = pl2 / DEGf;
    float s = sinf(t0), c = cosf(t0);
    float y_new = pl1 + po0*s + po1*c;
    float x_new = pl0 + po0*c - po1*s;
    float t_new = pl2 + po2*DEGf;
    t_new = fmodf(t_new - 180.0f, 360.0f) + 180.0f;
    t_new = fmodf(t_new + 180.0f, 360.0f) - 180.0f;
    out_p1[b*3+0]=x_new; out_p1[b*3+1]=y_new; out_p1[b*3+2]=t_new;
    out_p2[b*3+0]=x_new; out_p2[b*3+1]=y_new; out_p2[b*3+2]=t_new;
    float sx = -(((x_new*100.0f)/5.0f - 240.0f)/240.0f);
    float sy = -(((y_new*100.0f)/5.0f - 240.0f)/240.0f);
    float st_t = (90.0f - t_new) * 0.017453292519943295f;
    params[b*4+0] = cosf(st_t);
    params[b*4+1] = sinf(st_t);
    params[b*4+2] = sx;
    params[b*4+3] = sy;
}

// ---------------- per-pixel projection math ----------------
__device__ __forceinline__ float4 pixel_pos(const float* __restrict__ obsb,
                                            const float* __restrict__ sh,
                                            int b, int n, float fconst)
{
    int col = n % FWw, row = n / FWw;
    float depth = obsb[3*NPIX + n];
    const float4 s4 = ((const float4*)sh)[(size_t)b*NPIX + n];
    float sm = (((s4.x + s4.y) + s4.z) + s4.w) / 4.0f;
    float factor = 1.0f + sm;

    float X = ((float)col - 319.5f) * depth / fconst;
    float Z = ((float)(FHh-1-row) - 239.5f) * depth / fconst;
    float x_s = X + 250.0f;
    float z_s = Z + 88.0f;
    float xn = (x_s/5.0f - 50.0f)/100.0f*2.0f;
    float yn = (depth/5.0f - 50.0f)/100.0f*2.0f;
    float zn = (z_s/5.0f - 32.0f)/80.0f*2.0f;
    xn = fminf(fmaxf(xn,-1.0f),1.0f);
    yn = fminf(fmaxf(yn,-1.0f),1.0f);
    zn = fminf(fmaxf(zn,-1.0f),1.0f);
    float pos0 = (xn*100.0f)/2.0f + 50.0f;
    float pos1 = (yn*100.0f)/2.0f + 50.0f;
    float pos2 = (zn*80.0f)/2.0f + 40.0f;
    return make_float4(pos0, pos1, pos2, factor);
}

// Elements clipped to a boundary (pos==0/100/80) have zero weight everywhere.
__device__ __forceinline__ bool contributes(float4 P) {
    return (P.x > 0.0f && P.x < 100.0f &&
            P.y > 0.0f && P.y < 100.0f &&
            P.z > 0.0f && P.z < 80.0f);
}

// ---------------- pass A: bin counting (2 batches per pass) ----------------
__global__ void bin_count_kernel(const float* __restrict__ obs,
                                 const float* __restrict__ sh,
                                 int* __restrict__ counts,
                                 float fconst, int bbase)
{
    int g = blockIdx.x*blockDim.x + threadIdx.x;
    if (g >= 2*NPIX) return;
    int bh = g / NPIX, n = g % NPIX, b = bbase + bh;
    const float* obsb = obs + (size_t)b*COBS*NPIX;
    float4 P = pixel_pos(obsb, sh, b, n, fconst);
    if (!contributes(P)) return;
    int f0 = (int)floorf(P.x);     // 0..99 after filter
    int f1 = (int)floorf(P.y);
    atomicAdd(&counts[(bh*NBINS_DIM + f0)*NBINS_ROW + f1], 1);
}

// ---------------- exclusive scan (single block); also copies to cursor ----------------
__global__ void scan_kernel(int* __restrict__ counts, int* __restrict__ cursor)
{
    __shared__ int part[1024];
    int t = threadIdx.x;
    const int CHUNK = COUNTS_PAD / 1024;   // 20
    int base = t*CHUNK;
    int s = 0;
    for (int k = 0; k < CHUNK; ++k) s += counts[base+k];
    part[t] = s;
    __syncthreads();
    for (int off = 1; off < 1024; off <<= 1) {
        int v = (t >= off) ? part[t-off] : 0;
        __syncthreads();
        part[t] += v;
        __syncthreads();
    }
    int run = part[t] - s;
    for (int k = 0; k < CHUNK; ++k) {
        int c = counts[base+k];
        counts[base+k] = run;
        cursor[base+k] = run;
        run += c;
    }
}

// ---------------- pass C: scatter packed payload ----------------
__global__ void scatter_kernel(const float* __restrict__ obs,
                               const float* __restrict__ sh,
                               int* __restrict__ cursor,
                               float4* __restrict__ payloadPos,
                               float* __restrict__ payloadSem,
                               float fconst, int bbase)
{
    int g = blockIdx.x*blockDim.x + threadIdx.x;
    if (g >= 2*NPIX) return;
    int bh = g / NPIX, n = g % NPIX, b = bbase + bh;
    const float* obsb = obs + (size_t)b*COBS*NPIX;
    float4 P = pixel_pos(obsb, sh, b, n, fconst);
    if (!contributes(P)) return;
    int f0 = (int)floorf(P.x);
    int f1 = (int)floorf(P.y);
    int bid = (bh*NBINS_DIM + f0)*NBINS_ROW + f1;
    int dst = atomicAdd(&cursor[bid], 1);
    payloadPos[dst] = P;
    int fz = (int)floorf(P.z);
    if (fz >= MINZc-1 && fz < MAXZc) {      // some corner lands in z-window
        float* sp = payloadSem + (size_t)dst*NSEMC;
        #pragma unroll
        for (int c = 0; c < NSEMC; ++c)
            sp[c] = obsb[(4+c)*NPIX + n] * P.w;   // coalesced in n
    }
}

// ---------------- pass B: gather 2x2-cell tiles into LDS ----------------
__global__ __launch_bounds__(256)
void gather_kernel(const float4* __restrict__ payloadPos,
                   const float* __restrict__ payloadSem,
                   const int* __restrict__ offs,
                   float* __restrict__ avwin,
                   float* __restrict__ fp_out, int bbase)
{
    int tile = blockIdx.x;           // 0..2499
    int bh = blockIdx.y, b = bbase + bh;
    int ti = tile % 50, tj = tile / 50;
    int i0 = 2*ti, j0 = 2*tj;
    int tid = threadIdx.x;

    __shared__ float accS[4*272];    // per cell: 80 ch0-z + 16*12 sem
    for (int k = tid; k < 4*272; k += 256) accS[k] = 0.0f;
    __syncthreads();

    int f1lo = (j0 > 0) ? (j0-1) : 0;
    int f1hi = j0 + 1;               // <= 99
    #pragma unroll
    for (int t3 = 0; t3 < 3; ++t3) {
        int f0r = i0 - 1 + t3;
        if (f0r < 0) continue;
        int rb = (bh*NBINS_DIM + f0r)*NBINS_ROW;
        int s = offs[rb + f1lo];
        int e = offs[rb + f1hi + 1];
        for (int idx = s + tid; idx < e; idx += 256) {
            float4 P = payloadPos[idx];
            int fx = (int)floorf(P.x), fy = (int)floorf(P.y), fz = (int)floorf(P.z);
            float sem[NSEMC];
            bool semL = false;
            #pragma unroll
            for (int dz = 0; dz < 2; ++dz) {
                int cz = fz + dz;
                if (cz <= 0 || cz >= HZc) continue;
                float wz = 1.0f - fabsf(P.z - (float)cz);
                if (wz <= 0.0f) continue;
                bool zwin = (cz >= MINZc && cz < MAXZc);
                #pragma unroll
                for (int dy = 0; dy < 2; ++dy) {
                    int cy = fy + dy, jy = cy - j0;
                    if ((unsigned)jy > 1u || cy == 0) continue;
                    float wyz = wz * (1.0f - fabsf(P.y - (float)cy));
                    #pragma unroll
                    for (int dx = 0; dx < 2; ++dx) {
                        int cx = fx + dx, ix = cx - i0;
                        if ((unsigned)ix > 1u || cx == 0) continue;
                        float w = wyz * (1.0f - fabsf(P.x - (float)cx));
                        if (w <= 0.0f) continue;
                        int base = (jy*2 + ix)*272;
                        atomicAdd(&accS[base + cz], P.w * w);
                        if (zwin) {
                            if (!semL) {
                                #pragma unroll
                                for (int c = 0; c < NSEMC; ++c)
                                    sem[c] = payloadSem[(size_t)idx*NSEMC + c];
                                semL = true;
                            }
                            int zo = base + HZc + (cz - MINZc);
                            #pragma unroll
                            for (int c = 0; c < NSEMC; ++c)
                                atomicAdd(&accS[zo + c*ZW], sem[c] * w);
                        }
                    }
                }
            }
        }
    }
    __syncthreads();

    if (tid < 72) {
        int cellL = tid / 18, ch = tid % 18;
        int ci = i0 + (cellL & 1), cj = j0 + (cellL >> 1);
        const float* a = &accS[cellL*272];
        float* avb = avwin + (size_t)b*18*10000;
        int oidx = cj*VRc + ci;
        if (ch == 0) {
            float s0 = 0.0f;
            #pragma unroll
            for (int z = MINZc; z < MAXZc; ++z) s0 += rintf(a[z]);
            float v = fminf(fmaxf(s0, 0.0f), 1.0f);
            avb[oidx] = v;
            fp_out[(size_t)b*10000 + oidx] = v;
        } else if (ch == 1) {
            float s0 = 0.0f;
            for (int z = 0; z < HZc; ++z) s0 += rintf(a[z]);
            avb[10000 + oidx] = fminf(fmaxf(s0, 0.0f), 1.0f);
        } else {
            int c = ch - 2;
            float s0 = 0.0f;
            #pragma unroll
            for (int z = 0; z < ZW; ++z) s0 += rintf(a[HZc + c*ZW + z]);
            avb[ch*10000 + oidx] = fminf(fmaxf(s0/5.0f, 0.0f), 1.0f);
        }
    }
}

// ---------------- fused double grid_sample + max ----------------
__device__ __forceinline__ float grid1d(int i) {
    return (float)(-1.0 + (double)i * (2.0/479.0));
}

__global__ void map_kernel(const float* __restrict__ maps_last,
                           const float* __restrict__ avwin,
                           const float* __restrict__ params,
                           float* __restrict__ map_out)
{
    int t = blockIdx.x*blockDim.x + threadIdx.x;
    if (t >= NB*MAPC*MAPC) return;
    int w = t % MAPC;
    int h = (t / MAPC) % MAPC;
    int b = t / (MAPC*MAPC);
    float ct = params[b*4+0], st = params[b*4+1];
    float sx = params[b*4+2], sy = params[b*4+3];

    float xg = grid1d(w) + sx;
    float yg = grid1d(h) + sy;
    float xt = ((xg + 1.0f)*479.0f)/2.0f;
    float yt = ((yg + 1.0f)*479.0f)/2.0f;
    float xf = floorf(xt), yf = floorf(yt);

    float acc[18];
    #pragma unroll
    for (int k=0;k<18;k++) acc[k]=0.0f;
    const float* avb = avwin + (size_t)b*18*10000;

    #pragma unroll
    for (int oy=0; oy<2; ++oy) {
        #pragma unroll
        for (int ox=0; ox<2; ++ox) {
            float qx = xf + (float)ox, qy = yf + (float)oy;
            if (!(qx >= 0.0f && qx < 480.0f && qy >= 0.0f && qy < 480.0f)) continue;
            float wo = (ox ? (xt - xf) : (xf + 1.0f - xt))
                     * (oy ? (yt - yf) : (yf + 1.0f - yt));
            int oxi = (int)qx, oyi = (int)qy;
            float gxr = grid1d(oxi), gyr = grid1d(oyi);
            float xr = ct*gxr - st*gyr;
            float yr = st*gxr + ct*gyr;
            float xp = ((xr + 1.0f)*479.0f)/2.0f;
            float yp = ((yr + 1.0f)*479.0f)/2.0f;
            float xpf = floorf(xp), ypf = floorf(yp);
            float R[18];
            #pragma unroll
            for (int k=0;k<18;k++) R[k]=0.0f;
            #pragma unroll
            for (int iy=0; iy<2; ++iy) {
                #pragma unroll
                for (int ix=0; ix<2; ++ix) {
                    float rx = xpf + (float)ix, ry = ypf + (float)iy;
                    if (!(rx >= 0.0f && rx < 480.0f && ry >= 0.0f && ry < 480.0f)) continue;
                    int rxi = (int)rx, ryi = (int)ry;
                    if (ryi < 240 || ryi >= 340 || rxi < 190 || rxi >= 290) continue;
                    float wi = (ix ? (xp - xpf) : (xpf + 1.0f - xp))
                             * (iy ? (yp - ypf) : (ypf + 1.0f - yp));
                    const float* p = avb + (ryi-240)*VRc + (rxi-190);
                    #pragma unroll
                    for (int k=0;k<18;k++) R[k] += wi * p[k*10000];
                }
            }
            #pragma unroll
            for (int k=0;k<18;k++) acc[k] += wo * R[k];
        }
    }

    #pragma unroll
    for (int c=0;c<COBS;c++) {
        size_t o = (((size_t)b*COBS + c)*MAPC + h)*MAPC + w;
        float tv = (c==0) ? acc[0] : (c==1) ? acc[1] : (c>=4) ? acc[c-2] : 0.0f;
        map_out[o] = fmaxf(maps_last[o], tv);
    }
}

extern "C" void kernel_launch(void* const* d_in, const int* in_sizes, int n_in,
                              void* d_out, int out_size, void* d_ws, size_t ws_size,
                              hipStream_t stream)
{
    const float* obs        = (const float*)d_in[0];
    const float* pose_obs   = (const float*)d_in[1];
    const float* maps_last  = (const float*)d_in[2];
    const float* poses_last = (const float*)d_in[3];
    const float* sh         = (const float*)d_in[4];
    float* out = (float*)d_out;

    float* fp_out  = out;                       // B*1*100*100 = 40000
    float* map_out = out + 40000;               // B*20*480*480 = 18432000
    float* poses1  = out + 40000 + 18432000;    // 12
    float* poses2  = poses1 + 12;               // 12

    float* params = (float*)d_ws;               // 16 floats
    float* avwin  = params + 16;                // B*18*100*100 = 720000 floats

    // Scratch inside the map_pred output region (consumed before map_kernel).
    // Per pass (2 batches): up to 614,400 elements.
    const int NHALF = 2*NPIX;                   // 614,400
    float4* payloadPos = (float4*)map_out;                       // 2,457,600 floats
    float*  payloadSem = map_out + 2457600;                      // 9,830,400 floats
    int*    counts     = (int*)(map_out + 12288000);             // 20,480 ints
    int*    cursor     = (int*)(map_out + 12288000 + 20480);     // 20,480 ints
    // total 12,328,960 floats < 18,432,000 available

    double rad = 39.5 * 0.017453292519943295;
    float fconst = (float)(320.0 / tan(rad));

    hipLaunchKernelGGL(pose_kernel, dim3(1), dim3(64), 0, stream,
                       pose_obs, poses_last, poses1, poses2, params);

    for (int half = 0; half < 2; ++half) {
        int bbase = 2*half;
        hipMemsetAsync(counts, 0, (size_t)COUNTS_PAD*sizeof(int), stream);
        hipLaunchKernelGGL(bin_count_kernel, dim3((NHALF+255)/256), dim3(256), 0, stream,
                           obs, sh, counts, fconst, bbase);
        hipLaunchKernelGGL(scan_kernel, dim3(1), dim3(1024), 0, stream, counts, cursor);
        hipLaunchKernelGGL(scatter_kernel, dim3((NHALF+255)/256), dim3(256), 0, stream,
                           obs, sh, cursor, payloadPos, payloadSem, fconst, bbase);
        hipLaunchKernelGGL(gather_kernel, dim3(2500, 2), dim3(256), 0, stream,
                           payloadPos, payloadSem, counts, avwin, fp_out, bbase);
    }

    hipLaunchKernelGGL(map_kernel, dim3((NB*MAPC*MAPC+255)/256), dim3(256), 0, stream,
                       maps_last, avwin, params, map_out);
}